// Round 12
// baseline (212.322 us; speedup 1.0000x reference)
//
#include <hip/hip_runtime.h>
#include <stdint.h>

typedef __attribute__((ext_vector_type(8))) __bf16 bf16x8;
typedef __attribute__((ext_vector_type(4))) float f32x4;
typedef __attribute__((ext_vector_type(8))) unsigned short ushort8;
typedef __attribute__((ext_vector_type(4))) unsigned short ushort4v;
typedef unsigned short u16;
typedef unsigned int u32;

__device__ __forceinline__ u16 f2bf(float f) {
    __bf16 h = (__bf16)f;
    return __builtin_bit_cast(u16, h);
}

__device__ __forceinline__ f32x4 mfma16(bf16x8 a, bf16x8 b, f32x4 c) {
    return __builtin_amdgcn_mfma_f32_16x16x32_bf16(a, b, c, 0, 0, 0);
}

typedef __attribute__((address_space(1))) const char g_char;
typedef __attribute__((address_space(3))) char l_char;
__device__ __forceinline__ void gload_lds16(const void* g, void* l) {
    __builtin_amdgcn_global_load_lds((g_char*)g, (l_char*)l, 16, 0, 0);
}

// ---------------------------------------------------------------------------
// Weight prep:
//  WTs: K-blocked, XOR-pre-swizzled bf16 W^T for qkv_gemm B staging.
//    WTs_u16[kk*49152 + j*64 + (c ^ ((j&7)<<3))] = W_sel[kk*64+c][j%256]
//    (j<256: Wq, <512: Wk, <768: Wv; kk in 0..3, c in 0..63)
//  WOT[o][h] = Wo[h][o] as bf16 (for out_gemm, unchanged layout).
// ---------------------------------------------------------------------------
__global__ __launch_bounds__(256) void prep_w(
    const float* __restrict__ Wq, const float* __restrict__ Wk,
    const float* __restrict__ Wv, const float* __restrict__ Wo,
    u16* __restrict__ WTs, u16* __restrict__ WOT)
{
    int idx = blockIdx.x * 256 + threadIdx.x;  // 0..262143
    if (idx < 196608) {
        int j = idx >> 8, k = idx & 255;
        const float* W = (j < 256) ? Wq : (j < 512) ? Wk : Wv;
        u16 v = f2bf(W[k * 256 + (j & 255)]);
        int kk = k >> 6, c = k & 63;
        WTs[kk * 49152 + j * 64 + (c ^ ((j & 7) << 3))] = v;
    } else {
        int t = idx - 196608;
        int j = t >> 8, k = t & 255;
        WOT[t] = f2bf(Wo[k * 256 + j]);
    }
}

// ---------------------------------------------------------------------------
// QKV projection r12: m97-style 128x128 tile, BK=64, double-buffered LDS.
//  B tiles: contiguous pre-swizzled 16KB blocks of WTs -> 4 global_load_lds.
//  A tiles: f32 -> reg (issued early, T14) -> cvt -> ds_write (late).
//  5 barriers per block (vs 49 before). Grid 3072 = row*6 + colblk.
// ---------------------------------------------------------------------------
__global__ __launch_bounds__(256) void qkv_gemm(
    const float* __restrict__ X, const u16* __restrict__ WTs,
    const float* __restrict__ bQ, const float* __restrict__ bK,
    const float* __restrict__ bV,
    u16* __restrict__ outQ, u16* __restrict__ outK, u16* __restrict__ outVT)
{
    __shared__ __align__(16) u16 As[2][8192];  // 2 x 16KB [128 rows][64 K]
    __shared__ __align__(16) u16 Bs[2][8192];  // 2 x 16KB [128 cols][64 K]
    const int tid = threadIdx.x;
    const int bid = blockIdx.x;
    const int m0 = (bid / 6) * 128;      // row panel
    const int cbi = bid - (bid / 6) * 6; // 0..5 column block
    const int jbase = cbi * 128;

    const int lane = tid & 63, wid = tid >> 6;
    const int wr = wid >> 1, wc = wid & 1;
    const int lr = lane & 15, lg = lane >> 4;

    auto stageB = [&](int buf, int kk) {
        const char* src = reinterpret_cast<const char*>(
            WTs + (size_t)kk * 49152 + (size_t)jbase * 64);
        #pragma unroll
        for (int i = 0; i < 4; ++i) {
            int p = (i * 256 + tid) * 16;
            gload_lds16(src + p,
                reinterpret_cast<char*>(Bs[buf]) + i * 4096 + wid * 1024);
        }
    };

    f32x4 ar[8];
    auto issueA = [&](int kk) {
        #pragma unroll
        for (int i = 0; i < 8; ++i) {
            int e = (i * 256 + tid) * 4;
            int r = e >> 6, c = e & 63;
            ar[i] = *reinterpret_cast<const f32x4*>(
                X + (size_t)(m0 + r) * 256 + kk * 64 + c);
        }
    };
    auto writeA = [&](int buf) {
        #pragma unroll
        for (int i = 0; i < 8; ++i) {
            int e = (i * 256 + tid) * 4;
            int r = e >> 6, c = e & 63;
            ushort4v h;
            h.x = f2bf(ar[i].x); h.y = f2bf(ar[i].y);
            h.z = f2bf(ar[i].z); h.w = f2bf(ar[i].w);
            int byte = (r * 128 + c * 2) ^ ((r & 7) << 4);
            *reinterpret_cast<ushort4v*>(reinterpret_cast<char*>(As[buf]) + byte) = h;
        }
    };

    f32x4 acc[4][4];
    #pragma unroll
    for (int a = 0; a < 4; ++a)
        #pragma unroll
        for (int b = 0; b < 4; ++b) acc[a][b] = (f32x4){0.f, 0.f, 0.f, 0.f};

    // prologue: stage kk=0 into buf 0
    stageB(0, 0);
    issueA(0);
    writeA(0);
    __syncthreads();

    for (int kk = 0; kk < 4; ++kk) {
        const int cur = kk & 1;
        if (kk < 3) {
            stageB(cur ^ 1, kk + 1);  // async DMA into other buffer
            issueA(kk + 1);           // f32 loads in flight during compute
        }
        // compute from buf cur
        #pragma unroll
        for (int ks = 0; ks < 2; ++ks) {
            bf16x8 af[4], bfr[4];
            #pragma unroll
            for (int mt = 0; mt < 4; ++mt) {
                int r = wr * 64 + mt * 16 + lr;
                int byte = (r * 128 + ks * 64 + lg * 16) ^ ((r & 7) << 4);
                af[mt] = *reinterpret_cast<const bf16x8*>(
                    reinterpret_cast<const char*>(As[cur]) + byte);
            }
            #pragma unroll
            for (int nt = 0; nt < 4; ++nt) {
                int r = wc * 64 + nt * 16 + lr;
                int byte = (r * 128 + ks * 64 + lg * 16) ^ ((r & 7) << 4);
                bfr[nt] = *reinterpret_cast<const bf16x8*>(
                    reinterpret_cast<const char*>(Bs[cur]) + byte);
            }
            __builtin_amdgcn_s_setprio(1);
            #pragma unroll
            for (int mt = 0; mt < 4; ++mt)
                #pragma unroll
                for (int nt = 0; nt < 4; ++nt)
                    acc[mt][nt] = mfma16(af[mt], bfr[nt], acc[mt][nt]);
            __builtin_amdgcn_s_setprio(0);
        }
        if (kk < 3) writeA(cur ^ 1);  // cvt + LDS write (waits its loads)
        __syncthreads();              // DMA drained + writes visible
    }

    // epilogue: bias + relu + bf16 stores (identical semantics to r11)
    const float* bias = (cbi < 2) ? bQ : (cbi < 4) ? bK : bV;
    float bcol[4];
    #pragma unroll
    for (int nt = 0; nt < 4; ++nt)
        bcol[nt] = bias[(jbase + wc * 64 + nt * 16 + lr) & 255];
    #pragma unroll
    for (int mt = 0; mt < 4; ++mt) {
        #pragma unroll
        for (int nt = 0; nt < 4; ++nt) {
            #pragma unroll
            for (int j = 0; j < 4; ++j) {
                float v = fmaxf(acc[mt][nt][j] + bcol[nt], 0.f);
                u16 h = f2bf(v);
                int row = m0 + wr * 64 + mt * 16 + lg * 4 + j;
                int col = jbase + wc * 64 + nt * 16 + lr;
                if (cbi < 2) {
                    outQ[(size_t)row * 256 + col] = h;
                } else if (cbi < 4) {
                    outK[(size_t)row * 256 + (col - 256)] = h;
                } else {
                    int bb = row >> 9, n = row & 511;
                    outVT[(size_t)bb * 131072 + (size_t)(col - 512) * 512 + n] = h;
                }
            }
        }
    }
}

// ---------------------------------------------------------------------------
// Flash attention r11 (unchanged): swapped QK^T, scalar softmax, b64 P path.
// ---------------------------------------------------------------------------
__global__ __launch_bounds__(512) void attn_kernel(
    const u16* __restrict__ Q, const u16* __restrict__ K,
    const u16* __restrict__ VT, const float* __restrict__ Mask,
    u16* __restrict__ Out)
{
    __shared__ __align__(16) u16 k_lds[2][32 * 256];  // 2 x 16KB, XOR-swizzled
    __shared__ __align__(16) u16 v_lds[2][256 * 32];  // 2 x 16KB, chunk-swizzled
    __shared__ __align__(16) char p_lds[8 * 1280];    // per-wave [16 q][80B]
    const int tid = threadIdx.x;          // 0..511
    const int b  = blockIdx.x & 127;      // batch; 4 blocks/batch on one XCD
    const int rb = blockIdx.x >> 7;       // 0..3
    const int lane = tid & 63, wid = tid >> 6;
    const int lr = lane & 15, lg = lane >> 4;
    const int n0 = rb * 128 + wid * 16;
    const u16* qbat = Q  + (size_t)b * 131072;
    const u16* kbat = K  + (size_t)b * 131072;
    const u16* vbat = VT + (size_t)b * 131072;
    const float* mbase = Mask + ((size_t)b * 512 + n0 + lr) * 512;
    char* pw = p_lds + wid * 1280;

    auto stage = [&](int buf, int kt) {
        #pragma unroll
        for (int i = 0; i < 2; ++i) {
            int p = (i * 512 + tid) * 16;
            int krow = p >> 9, kcol2 = p & 511;
            int scol2 = kcol2 ^ ((krow & 7) << 4);
            const char* gk = reinterpret_cast<const char*>(kbat + (size_t)(kt * 32 + krow) * 256) + scol2;
            char* lk = reinterpret_cast<char*>(k_lds[buf]) + i * 8192 + wid * 1024;
            gload_lds16(gk, lk);
            int vrow = p >> 6;
            int chunk = (p >> 4) & 3;
            int schunk = chunk ^ (vrow & 3);
            const char* gv = reinterpret_cast<const char*>(vbat + (size_t)vrow * 512 + kt * 32) + schunk * 16;
            char* lv = reinterpret_cast<char*>(v_lds[buf]) + i * 8192 + wid * 1024;
            gload_lds16(gv, lv);
        }
    };

    bf16x8 qf[8];
    #pragma unroll
    for (int ks = 0; ks < 8; ++ks)
        qf[ks] = *reinterpret_cast<const bf16x8*>(
            qbat + (size_t)(n0 + lr) * 256 + ks * 32 + lg * 8);

    stage(0, 0);
    f32x4 mf[2];
    #pragma unroll
    for (int ct = 0; ct < 2; ++ct)
        mf[ct] = __builtin_nontemporal_load(
            reinterpret_cast<const f32x4*>(mbase + ct * 16 + lg * 4));

    f32x4 acc[16];
    #pragma unroll
    for (int i = 0; i < 16; ++i) acc[i] = (f32x4){0.f, 0.f, 0.f, 0.f};
    float mreg = -__builtin_inff(), lreg = 0.f;

    __syncthreads();

    for (int kt = 0; kt < 16; ++kt) {
        const int cur = kt & 1;
        if (kt < 15) stage(cur ^ 1, kt + 1);

        u32 mb = 0;
        #pragma unroll
        for (int ct = 0; ct < 2; ++ct)
            #pragma unroll
            for (int j = 0; j < 4; ++j)
                mb |= (mf[ct][j] > 0.5f ? 1u : 0u) << (ct * 4 + j);
        if (kt < 15) {
            #pragma unroll
            for (int ct = 0; ct < 2; ++ct)
                mf[ct] = __builtin_nontemporal_load(reinterpret_cast<const f32x4*>(
                    mbase + (kt + 1) * 32 + ct * 16 + lg * 4));
        }

        f32x4 s[2];
        s[0] = (f32x4){0.f, 0.f, 0.f, 0.f};
        s[1] = (f32x4){0.f, 0.f, 0.f, 0.f};
        const char* kbase = reinterpret_cast<const char*>(k_lds[cur]);
        __builtin_amdgcn_s_setprio(1);
        #pragma unroll
        for (int ks = 0; ks < 8; ++ks) {
            #pragma unroll
            for (int ct = 0; ct < 2; ++ct) {
                int krow = ct * 16 + lr;
                int byte = (krow * 512 + (ks * 32 + lg * 8) * 2) ^ ((krow & 7) << 4);
                bf16x8 kf = *reinterpret_cast<const bf16x8*>(kbase + byte);
                s[ct] = mfma16(kf, qf[ks], s[ct]);   // SWAPPED: D = S^T
            }
        }
        __builtin_amdgcn_s_setprio(0);

        float p[2][4];
        #pragma unroll
        for (int ct = 0; ct < 2; ++ct)
            #pragma unroll
            for (int j = 0; j < 4; ++j)
                p[ct][j] = ((mb >> (ct * 4 + j)) & 1u) ? s[ct][j] : -9.0e15f;

        float r0 = p[0][0];
        r0 = fmaxf(r0, p[0][1]); r0 = fmaxf(r0, p[0][2]); r0 = fmaxf(r0, p[0][3]);
        r0 = fmaxf(r0, p[1][0]); r0 = fmaxf(r0, p[1][1]);
        r0 = fmaxf(r0, p[1][2]); r0 = fmaxf(r0, p[1][3]);
        r0 = fmaxf(r0, __shfl_xor(r0, 16));
        r0 = fmaxf(r0, __shfl_xor(r0, 32));
        bool need = (r0 > mreg);
        if (__any(need)) {
            float mnew = fmaxf(mreg, r0);
            float sc = __expf(mreg - mnew);
            mreg = mnew;
            lreg *= sc;
            #pragma unroll
            for (int ht = 0; ht < 16; ++ht) {
                acc[ht][0] *= sc; acc[ht][1] *= sc;
                acc[ht][2] *= sc; acc[ht][3] *= sc;
            }
        }
        float ps = 0.f;
        #pragma unroll
        for (int ct = 0; ct < 2; ++ct)
            #pragma unroll
            for (int j = 0; j < 4; ++j) {
                float e = __expf(p[ct][j] - mreg);
                p[ct][j] = e;
                ps += e;
            }
        lreg += ps;

        #pragma unroll
        for (int ct = 0; ct < 2; ++ct) {
            ushort4v w;
            w.x = f2bf(p[ct][0]); w.y = f2bf(p[ct][1]);
            w.z = f2bf(p[ct][2]); w.w = f2bf(p[ct][3]);
            *reinterpret_cast<ushort4v*>(pw + lr * 80 + ct * 32 + lg * 8) = w;
        }

        bf16x8 pf = *reinterpret_cast<const bf16x8*>(pw + lr * 80 + lg * 16);
        const char* vbase = reinterpret_cast<const char*>(v_lds[cur]);
        __builtin_amdgcn_s_setprio(1);
        #pragma unroll
        for (int ht = 0; ht < 16; ++ht) {
            int hrow = ht * 16 + lr;
            int byte = (hrow * 64 + lg * 16) ^ ((hrow & 3) << 4);
            bf16x8 vf = *reinterpret_cast<const bf16x8*>(vbase + byte);
            acc[ht] = mfma16(vf, pf, acc[ht]);
        }
        __builtin_amdgcn_s_setprio(0);

        __syncthreads();
    }

    float lt = lreg;
    lt += __shfl_xor(lt, 16);
    lt += __shfl_xor(lt, 32);
    float inv = 1.0f / lt;
    u16* orow = Out + ((size_t)b * 512 + n0 + lr) * 256;
    #pragma unroll
    for (int ht = 0; ht < 16; ++ht) {
        ushort4v w;
        w.x = f2bf(acc[ht][0] * inv); w.y = f2bf(acc[ht][1] * inv);
        w.z = f2bf(acc[ht][2] * inv); w.w = f2bf(acc[ht][3] * inv);
        *reinterpret_cast<ushort4v*>(orow + ht * 16 + lg * 4) = w;
    }
}

// ---------------------------------------------------------------------------
// Output projection: Out[65536,256] = relu(A[65536,256](bf16) @ Wo + bo), f32.
// ---------------------------------------------------------------------------
__global__ __launch_bounds__(256, 2) void out_gemm(
    const u16* __restrict__ A, const u16* __restrict__ WOT,
    const float* __restrict__ bO, float* __restrict__ Out)
{
    __shared__ __align__(16) u16 As[128 * 256];
    __shared__ __align__(16) u16 Bs[128 * 64];
    const int tid = threadIdx.x;
    const int m0 = blockIdx.x * 128;

    #pragma unroll
    for (int i = 0; i < 16; ++i) {
        int e = (i * 256 + tid) * 8;
        int r = e >> 8, c = e & 255;
        ushort8 d = *reinterpret_cast<const ushort8*>(A + (size_t)(m0 + r) * 256 + c);
        int byte = (r * 512 + c * 2) ^ ((r & 7) << 4);
        *reinterpret_cast<ushort8*>(reinterpret_cast<char*>(As) + byte) = d;
    }

    const int lane = tid & 63, wid = tid >> 6;
    const int wr = wid >> 1, wc = wid & 1;
    const int lr = lane & 15, lg = lane >> 4;

    for (int cb = 0; cb < 2; ++cb) {
        const int jbase = cb * 128;
        f32x4 acc[4][4];
        #pragma unroll
        for (int a = 0; a < 4; ++a)
            #pragma unroll
            for (int b = 0; b < 4; ++b) acc[a][b] = (f32x4){0.f, 0.f, 0.f, 0.f};

        for (int kk = 0; kk < 256; kk += 64) {
            __syncthreads();
            #pragma unroll
            for (int i = 0; i < 4; ++i) {
                int e = (i * 256 + tid) * 8;
                int r = e >> 6, c = e & 63;
                ushort8 d = *reinterpret_cast<const ushort8*>(WOT + (size_t)(jbase + r) * 256 + kk + c);
                int byte = (r * 128 + c * 2) ^ ((r & 7) << 4);
                *reinterpret_cast<ushort8*>(reinterpret_cast<char*>(Bs) + byte) = d;
            }
            __syncthreads();
            #pragma unroll
            for (int ks = 0; ks < 2; ++ks) {
                bf16x8 af[4], bfr[4];
                #pragma unroll
                for (int mt = 0; mt < 4; ++mt) {
                    int r = wr * 64 + mt * 16 + lr;
                    int byte = (r * 512 + (kk + ks * 32 + lg * 8) * 2) ^ ((r & 7) << 4);
                    af[mt] = *reinterpret_cast<const bf16x8*>(reinterpret_cast<const char*>(As) + byte);
                }
                #pragma unroll
                for (int nt = 0; nt < 4; ++nt) {
                    int r = wc * 64 + nt * 16 + lr;
                    int byte = (r * 128 + (ks * 32 + lg * 8) * 2) ^ ((r & 7) << 4);
                    bfr[nt] = *reinterpret_cast<const bf16x8*>(reinterpret_cast<const char*>(Bs) + byte);
                }
                #pragma unroll
                for (int mt = 0; mt < 4; ++mt)
                    #pragma unroll
                    for (int nt = 0; nt < 4; ++nt)
                        acc[mt][nt] = mfma16(af[mt], bfr[nt], acc[mt][nt]);
            }
        }
        float bcol[4];
        #pragma unroll
        for (int nt = 0; nt < 4; ++nt)
            bcol[nt] = bO[jbase + wc * 64 + nt * 16 + lr];
        #pragma unroll
        for (int mt = 0; mt < 4; ++mt) {
            #pragma unroll
            for (int nt = 0; nt < 4; ++nt) {
                #pragma unroll
                for (int j = 0; j < 4; ++j) {
                    float v = fmaxf(acc[mt][nt][j] + bcol[nt], 0.f);
                    int row = m0 + wr * 64 + mt * 16 + lg * 4 + j;
                    int col = jbase + wc * 64 + nt * 16 + lr;
                    Out[(size_t)row * 256 + col] = v;
                }
            }
        }
    }
}

// ---------------------------------------------------------------------------
extern "C" void kernel_launch(void* const* d_in, const int* in_sizes, int n_in,
                              void* d_out, int out_size, void* d_ws, size_t ws_size,
                              hipStream_t stream) {
    const float* x    = (const float*)d_in[0];
    const float* mask = (const float*)d_in[1];
    const float* Wv   = (const float*)d_in[2];
    const float* bv   = (const float*)d_in[3];
    const float* Wk   = (const float*)d_in[4];
    const float* bk   = (const float*)d_in[5];
    const float* Wq   = (const float*)d_in[6];
    const float* bq   = (const float*)d_in[7];
    const float* Wo   = (const float*)d_in[8];
    const float* bo   = (const float*)d_in[9];
    float* out = (float*)d_out;

    char* ws = (char*)d_ws;
    u16* WTs = (u16*)(ws);                          // 384KB K-blocked swizzled
    u16* WOT = (u16*)(ws + 393216);                 // 128KB
    u16* Qb  = (u16*)(ws + 524288);                 // 33.55MB (also attn out)
    u16* Kb  = (u16*)(ws + 524288 + 33554432);      // 33.55MB
    u16* VTb = (u16*)(ws + 524288 + 2 * 33554432);  // 33.55MB, [b][h][n]

    prep_w<<<1024, 256, 0, stream>>>(Wq, Wk, Wv, Wo, WTs, WOT);
    qkv_gemm<<<3072, 256, 0, stream>>>(x, WTs, bq, bk, bv, Qb, Kb, VTb);
    attn_kernel<<<512, 512, 0, stream>>>(Qb, Kb, VTb, mask, Qb);
    out_gemm<<<512, 256, 0, stream>>>(Qb, WOT, bo, out);
}

// Round 13
// 207.958 us; speedup vs baseline: 1.0210x; 1.0210x over previous
//
#include <hip/hip_runtime.h>
#include <stdint.h>

typedef __attribute__((ext_vector_type(8))) __bf16 bf16x8;
typedef __attribute__((ext_vector_type(4))) float f32x4;
typedef __attribute__((ext_vector_type(8))) unsigned short ushort8;
typedef __attribute__((ext_vector_type(4))) unsigned short ushort4v;
typedef unsigned short u16;
typedef unsigned int u32;

__device__ __forceinline__ u16 f2bf(float f) {
    __bf16 h = (__bf16)f;
    return __builtin_bit_cast(u16, h);
}

__device__ __forceinline__ f32x4 mfma16(bf16x8 a, bf16x8 b, f32x4 c) {
    return __builtin_amdgcn_mfma_f32_16x16x32_bf16(a, b, c, 0, 0, 0);
}

typedef __attribute__((address_space(1))) const char g_char;
typedef __attribute__((address_space(3))) char l_char;
__device__ __forceinline__ void gload_lds16(const void* g, void* l) {
    __builtin_amdgcn_global_load_lds((g_char*)g, (l_char*)l, 16, 0, 0);
}

// ---------------------------------------------------------------------------
// Weight prep (unchanged from r12):
//  WTs: K-blocked, XOR-pre-swizzled bf16 W^T.
//    WTs_u16[kk*49152 + j*64 + (c ^ ((j&7)<<3))] = W_sel[kk*64+c][j%256]
//  WOT[o][h] = Wo[h][o] as bf16.
// ---------------------------------------------------------------------------
__global__ __launch_bounds__(256) void prep_w(
    const float* __restrict__ Wq, const float* __restrict__ Wk,
    const float* __restrict__ Wv, const float* __restrict__ Wo,
    u16* __restrict__ WTs, u16* __restrict__ WOT)
{
    int idx = blockIdx.x * 256 + threadIdx.x;  // 0..262143
    if (idx < 196608) {
        int j = idx >> 8, k = idx & 255;
        const float* W = (j < 256) ? Wq : (j < 512) ? Wk : Wv;
        u16 v = f2bf(W[k * 256 + (j & 255)]);
        int kk = k >> 6, c = k & 63;
        WTs[kk * 49152 + j * 64 + (c ^ ((j & 7) << 3))] = v;
    } else {
        int t = idx - 196608;
        int j = t >> 8, k = t & 255;
        WOT[t] = f2bf(Wo[k * 256 + j]);
    }
}

// ---------------------------------------------------------------------------
// QKV projection r13: one block = 128 rows x ALL 768 cols (A read once),
// A staged once into 64KB swizzled LDS; B tiles (16KB, pre-swizzled) double-
// buffered via global_load_lds; 24 steps x 1 barrier. Grid 512.
// ---------------------------------------------------------------------------
__global__ __launch_bounds__(256) void qkv_gemm(
    const float* __restrict__ X, const u16* __restrict__ WTs,
    const float* __restrict__ bQ, const float* __restrict__ bK,
    const float* __restrict__ bV,
    u16* __restrict__ outQ, u16* __restrict__ outK, u16* __restrict__ outVT)
{
    __shared__ __align__(16) u16 As[128 * 256];  // 64KB, rows 512B, XOR-swizzled
    __shared__ __align__(16) u16 Bs[2][8192];    // 2 x 16KB, rows 128B, pre-swizzled
    const int tid = threadIdx.x;
    const int m0 = blockIdx.x * 128;

    // ---- stage A once: f32 -> bf16 -> swizzled LDS ----
    #pragma unroll
    for (int i = 0; i < 32; ++i) {
        int flat = (i * 256 + tid) * 4;
        int r = flat >> 8, c = flat & 255;
        const f32x4 f = *reinterpret_cast<const f32x4*>(X + (size_t)(m0 + r) * 256 + c);
        ushort4v h;
        h.x = f2bf(f.x); h.y = f2bf(f.y); h.z = f2bf(f.z); h.w = f2bf(f.w);
        int byte = (r * 512 + c * 2) ^ ((r & 7) << 4);
        *reinterpret_cast<ushort4v*>(reinterpret_cast<char*>(As) + byte) = h;
    }

    const int lane = tid & 63, wid = tid >> 6;
    const int wr = wid >> 1, wc = wid & 1;
    const int lr = lane & 15, lg = lane >> 4;

    auto stageB = [&](int buf, int cb, int kk) {
        const char* src = reinterpret_cast<const char*>(
            WTs + (size_t)kk * 49152 + (size_t)cb * 128 * 64);
        #pragma unroll
        for (int i = 0; i < 4; ++i) {
            int p = (i * 256 + tid) * 16;
            gload_lds16(src + p,
                reinterpret_cast<char*>(Bs[buf]) + i * 4096 + wid * 1024);
        }
    };

    stageB(0, 0, 0);
    __syncthreads();  // A writes visible + first B tile landed

    for (int cb = 0; cb < 6; ++cb) {
        const int jbase = cb * 128;
        f32x4 acc[4][4];
        #pragma unroll
        for (int a = 0; a < 4; ++a)
            #pragma unroll
            for (int b = 0; b < 4; ++b) acc[a][b] = (f32x4){0.f, 0.f, 0.f, 0.f};

        for (int kk = 0; kk < 4; ++kk) {
            const int t = cb * 4 + kk;
            const int cur = t & 1;
            if (t < 23) {
                const int nt_ = t + 1;
                stageB(cur ^ 1, nt_ >> 2, nt_ & 3);  // async DMA, other buffer
            }
            #pragma unroll
            for (int ks = 0; ks < 2; ++ks) {
                bf16x8 af[4], bfr[4];
                #pragma unroll
                for (int mt = 0; mt < 4; ++mt) {
                    int r = wr * 64 + mt * 16 + lr;
                    int byte = (r * 512 + (kk * 64 + ks * 32 + lg * 8) * 2) ^ ((r & 7) << 4);
                    af[mt] = *reinterpret_cast<const bf16x8*>(
                        reinterpret_cast<const char*>(As) + byte);
                }
                #pragma unroll
                for (int nt = 0; nt < 4; ++nt) {
                    int r = wc * 64 + nt * 16 + lr;
                    int byte = (r * 128 + ks * 64 + lg * 16) ^ ((r & 7) << 4);
                    bfr[nt] = *reinterpret_cast<const bf16x8*>(
                        reinterpret_cast<const char*>(Bs[cur]) + byte);
                }
                __builtin_amdgcn_s_setprio(1);
                #pragma unroll
                for (int mt = 0; mt < 4; ++mt)
                    #pragma unroll
                    for (int nt = 0; nt < 4; ++nt)
                        acc[mt][nt] = mfma16(af[mt], bfr[nt], acc[mt][nt]);
                __builtin_amdgcn_s_setprio(0);
            }
            __syncthreads();  // next B landed; Bs[cur] readers done
        }

        // epilogue for this cb: bias + relu + bf16 stores
        const float* bias = (cb < 2) ? bQ : (cb < 4) ? bK : bV;
        float bcol[4];
        #pragma unroll
        for (int nt = 0; nt < 4; ++nt)
            bcol[nt] = bias[(jbase + wc * 64 + nt * 16 + lr) & 255];
        #pragma unroll
        for (int mt = 0; mt < 4; ++mt) {
            #pragma unroll
            for (int nt = 0; nt < 4; ++nt) {
                #pragma unroll
                for (int j = 0; j < 4; ++j) {
                    float v = fmaxf(acc[mt][nt][j] + bcol[nt], 0.f);
                    u16 h = f2bf(v);
                    int row = m0 + wr * 64 + mt * 16 + lg * 4 + j;
                    int col = jbase + wc * 64 + nt * 16 + lr;
                    if (cb < 2) {
                        outQ[(size_t)row * 256 + col] = h;
                    } else if (cb < 4) {
                        outK[(size_t)row * 256 + (col - 256)] = h;
                    } else {
                        int bb = row >> 9, n = row & 511;
                        outVT[(size_t)bb * 131072 + (size_t)(col - 512) * 512 + n] = h;
                    }
                }
            }
        }
    }
}

// ---------------------------------------------------------------------------
// Flash attention r11 (unchanged): swapped QK^T, scalar softmax, b64 P path.
// ---------------------------------------------------------------------------
__global__ __launch_bounds__(512) void attn_kernel(
    const u16* __restrict__ Q, const u16* __restrict__ K,
    const u16* __restrict__ VT, const float* __restrict__ Mask,
    u16* __restrict__ Out)
{
    __shared__ __align__(16) u16 k_lds[2][32 * 256];  // 2 x 16KB, XOR-swizzled
    __shared__ __align__(16) u16 v_lds[2][256 * 32];  // 2 x 16KB, chunk-swizzled
    __shared__ __align__(16) char p_lds[8 * 1280];    // per-wave [16 q][80B]
    const int tid = threadIdx.x;          // 0..511
    const int b  = blockIdx.x & 127;      // batch; 4 blocks/batch on one XCD
    const int rb = blockIdx.x >> 7;       // 0..3
    const int lane = tid & 63, wid = tid >> 6;
    const int lr = lane & 15, lg = lane >> 4;
    const int n0 = rb * 128 + wid * 16;
    const u16* qbat = Q  + (size_t)b * 131072;
    const u16* kbat = K  + (size_t)b * 131072;
    const u16* vbat = VT + (size_t)b * 131072;
    const float* mbase = Mask + ((size_t)b * 512 + n0 + lr) * 512;
    char* pw = p_lds + wid * 1280;

    auto stage = [&](int buf, int kt) {
        #pragma unroll
        for (int i = 0; i < 2; ++i) {
            int p = (i * 512 + tid) * 16;
            int krow = p >> 9, kcol2 = p & 511;
            int scol2 = kcol2 ^ ((krow & 7) << 4);
            const char* gk = reinterpret_cast<const char*>(kbat + (size_t)(kt * 32 + krow) * 256) + scol2;
            char* lk = reinterpret_cast<char*>(k_lds[buf]) + i * 8192 + wid * 1024;
            gload_lds16(gk, lk);
            int vrow = p >> 6;
            int chunk = (p >> 4) & 3;
            int schunk = chunk ^ (vrow & 3);
            const char* gv = reinterpret_cast<const char*>(vbat + (size_t)vrow * 512 + kt * 32) + schunk * 16;
            char* lv = reinterpret_cast<char*>(v_lds[buf]) + i * 8192 + wid * 1024;
            gload_lds16(gv, lv);
        }
    };

    bf16x8 qf[8];
    #pragma unroll
    for (int ks = 0; ks < 8; ++ks)
        qf[ks] = *reinterpret_cast<const bf16x8*>(
            qbat + (size_t)(n0 + lr) * 256 + ks * 32 + lg * 8);

    stage(0, 0);
    f32x4 mf[2];
    #pragma unroll
    for (int ct = 0; ct < 2; ++ct)
        mf[ct] = __builtin_nontemporal_load(
            reinterpret_cast<const f32x4*>(mbase + ct * 16 + lg * 4));

    f32x4 acc[16];
    #pragma unroll
    for (int i = 0; i < 16; ++i) acc[i] = (f32x4){0.f, 0.f, 0.f, 0.f};
    float mreg = -__builtin_inff(), lreg = 0.f;

    __syncthreads();

    for (int kt = 0; kt < 16; ++kt) {
        const int cur = kt & 1;
        if (kt < 15) stage(cur ^ 1, kt + 1);

        u32 mb = 0;
        #pragma unroll
        for (int ct = 0; ct < 2; ++ct)
            #pragma unroll
            for (int j = 0; j < 4; ++j)
                mb |= (mf[ct][j] > 0.5f ? 1u : 0u) << (ct * 4 + j);
        if (kt < 15) {
            #pragma unroll
            for (int ct = 0; ct < 2; ++ct)
                mf[ct] = __builtin_nontemporal_load(reinterpret_cast<const f32x4*>(
                    mbase + (kt + 1) * 32 + ct * 16 + lg * 4));
        }

        f32x4 s[2];
        s[0] = (f32x4){0.f, 0.f, 0.f, 0.f};
        s[1] = (f32x4){0.f, 0.f, 0.f, 0.f};
        const char* kbase = reinterpret_cast<const char*>(k_lds[cur]);
        __builtin_amdgcn_s_setprio(1);
        #pragma unroll
        for (int ks = 0; ks < 8; ++ks) {
            #pragma unroll
            for (int ct = 0; ct < 2; ++ct) {
                int krow = ct * 16 + lr;
                int byte = (krow * 512 + (ks * 32 + lg * 8) * 2) ^ ((krow & 7) << 4);
                bf16x8 kf = *reinterpret_cast<const bf16x8*>(kbase + byte);
                s[ct] = mfma16(kf, qf[ks], s[ct]);   // SWAPPED: D = S^T
            }
        }
        __builtin_amdgcn_s_setprio(0);

        float p[2][4];
        #pragma unroll
        for (int ct = 0; ct < 2; ++ct)
            #pragma unroll
            for (int j = 0; j < 4; ++j)
                p[ct][j] = ((mb >> (ct * 4 + j)) & 1u) ? s[ct][j] : -9.0e15f;

        float r0 = p[0][0];
        r0 = fmaxf(r0, p[0][1]); r0 = fmaxf(r0, p[0][2]); r0 = fmaxf(r0, p[0][3]);
        r0 = fmaxf(r0, p[1][0]); r0 = fmaxf(r0, p[1][1]);
        r0 = fmaxf(r0, p[1][2]); r0 = fmaxf(r0, p[1][3]);
        r0 = fmaxf(r0, __shfl_xor(r0, 16));
        r0 = fmaxf(r0, __shfl_xor(r0, 32));
        bool need = (r0 > mreg);
        if (__any(need)) {
            float mnew = fmaxf(mreg, r0);
            float sc = __expf(mreg - mnew);
            mreg = mnew;
            lreg *= sc;
            #pragma unroll
            for (int ht = 0; ht < 16; ++ht) {
                acc[ht][0] *= sc; acc[ht][1] *= sc;
                acc[ht][2] *= sc; acc[ht][3] *= sc;
            }
        }
        float ps = 0.f;
        #pragma unroll
        for (int ct = 0; ct < 2; ++ct)
            #pragma unroll
            for (int j = 0; j < 4; ++j) {
                float e = __expf(p[ct][j] - mreg);
                p[ct][j] = e;
                ps += e;
            }
        lreg += ps;

        #pragma unroll
        for (int ct = 0; ct < 2; ++ct) {
            ushort4v w;
            w.x = f2bf(p[ct][0]); w.y = f2bf(p[ct][1]);
            w.z = f2bf(p[ct][2]); w.w = f2bf(p[ct][3]);
            *reinterpret_cast<ushort4v*>(pw + lr * 80 + ct * 32 + lg * 8) = w;
        }

        bf16x8 pf = *reinterpret_cast<const bf16x8*>(pw + lr * 80 + lg * 16);
        const char* vbase = reinterpret_cast<const char*>(v_lds[cur]);
        __builtin_amdgcn_s_setprio(1);
        #pragma unroll
        for (int ht = 0; ht < 16; ++ht) {
            int hrow = ht * 16 + lr;
            int byte = (hrow * 64 + lg * 16) ^ ((hrow & 3) << 4);
            bf16x8 vf = *reinterpret_cast<const bf16x8*>(vbase + byte);
            acc[ht] = mfma16(vf, pf, acc[ht]);
        }
        __builtin_amdgcn_s_setprio(0);

        __syncthreads();
    }

    float lt = lreg;
    lt += __shfl_xor(lt, 16);
    lt += __shfl_xor(lt, 32);
    float inv = 1.0f / lt;
    u16* orow = Out + ((size_t)b * 512 + n0 + lr) * 256;
    #pragma unroll
    for (int ht = 0; ht < 16; ++ht) {
        ushort4v w;
        w.x = f2bf(acc[ht][0] * inv); w.y = f2bf(acc[ht][1] * inv);
        w.z = f2bf(acc[ht][2] * inv); w.w = f2bf(acc[ht][3] * inv);
        *reinterpret_cast<ushort4v*>(orow + ht * 16 + lg * 4) = w;
    }
}

// ---------------------------------------------------------------------------
// Output projection: Out[65536,256] = relu(A[65536,256](bf16) @ Wo + bo), f32.
// ---------------------------------------------------------------------------
__global__ __launch_bounds__(256, 2) void out_gemm(
    const u16* __restrict__ A, const u16* __restrict__ WOT,
    const float* __restrict__ bO, float* __restrict__ Out)
{
    __shared__ __align__(16) u16 As[128 * 256];
    __shared__ __align__(16) u16 Bs[128 * 64];
    const int tid = threadIdx.x;
    const int m0 = blockIdx.x * 128;

    #pragma unroll
    for (int i = 0; i < 16; ++i) {
        int e = (i * 256 + tid) * 8;
        int r = e >> 8, c = e & 255;
        ushort8 d = *reinterpret_cast<const ushort8*>(A + (size_t)(m0 + r) * 256 + c);
        int byte = (r * 512 + c * 2) ^ ((r & 7) << 4);
        *reinterpret_cast<ushort8*>(reinterpret_cast<char*>(As) + byte) = d;
    }

    const int lane = tid & 63, wid = tid >> 6;
    const int wr = wid >> 1, wc = wid & 1;
    const int lr = lane & 15, lg = lane >> 4;

    for (int cb = 0; cb < 2; ++cb) {
        const int jbase = cb * 128;
        f32x4 acc[4][4];
        #pragma unroll
        for (int a = 0; a < 4; ++a)
            #pragma unroll
            for (int b = 0; b < 4; ++b) acc[a][b] = (f32x4){0.f, 0.f, 0.f, 0.f};

        for (int kk = 0; kk < 256; kk += 64) {
            __syncthreads();
            #pragma unroll
            for (int i = 0; i < 4; ++i) {
                int e = (i * 256 + tid) * 8;
                int r = e >> 6, c = e & 63;
                ushort8 d = *reinterpret_cast<const ushort8*>(WOT + (size_t)(jbase + r) * 256 + kk + c);
                int byte = (r * 128 + c * 2) ^ ((r & 7) << 4);
                *reinterpret_cast<ushort8*>(reinterpret_cast<char*>(Bs) + byte) = d;
            }
            __syncthreads();
            #pragma unroll
            for (int ks = 0; ks < 2; ++ks) {
                bf16x8 af[4], bfr[4];
                #pragma unroll
                for (int mt = 0; mt < 4; ++mt) {
                    int r = wr * 64 + mt * 16 + lr;
                    int byte = (r * 512 + (kk + ks * 32 + lg * 8) * 2) ^ ((r & 7) << 4);
                    af[mt] = *reinterpret_cast<const bf16x8*>(reinterpret_cast<const char*>(As) + byte);
                }
                #pragma unroll
                for (int nt = 0; nt < 4; ++nt) {
                    int r = wc * 64 + nt * 16 + lr;
                    int byte = (r * 128 + (ks * 32 + lg * 8) * 2) ^ ((r & 7) << 4);
                    bfr[nt] = *reinterpret_cast<const bf16x8*>(reinterpret_cast<const char*>(Bs) + byte);
                }
                #pragma unroll
                for (int mt = 0; mt < 4; ++mt)
                    #pragma unroll
                    for (int nt = 0; nt < 4; ++nt)
                        acc[mt][nt] = mfma16(af[mt], bfr[nt], acc[mt][nt]);
            }
        }
        float bcol[4];
        #pragma unroll
        for (int nt = 0; nt < 4; ++nt)
            bcol[nt] = bO[jbase + wc * 64 + nt * 16 + lr];
        #pragma unroll
        for (int mt = 0; mt < 4; ++mt) {
            #pragma unroll
            for (int nt = 0; nt < 4; ++nt) {
                #pragma unroll
                for (int j = 0; j < 4; ++j) {
                    float v = fmaxf(acc[mt][nt][j] + bcol[nt], 0.f);
                    int row = m0 + wr * 64 + mt * 16 + lg * 4 + j;
                    int col = jbase + wc * 64 + nt * 16 + lr;
                    Out[(size_t)row * 256 + col] = v;
                }
            }
        }
    }
}

// ---------------------------------------------------------------------------
extern "C" void kernel_launch(void* const* d_in, const int* in_sizes, int n_in,
                              void* d_out, int out_size, void* d_ws, size_t ws_size,
                              hipStream_t stream) {
    const float* x    = (const float*)d_in[0];
    const float* mask = (const float*)d_in[1];
    const float* Wv   = (const float*)d_in[2];
    const float* bv   = (const float*)d_in[3];
    const float* Wk   = (const float*)d_in[4];
    const float* bk   = (const float*)d_in[5];
    const float* Wq   = (const float*)d_in[6];
    const float* bq   = (const float*)d_in[7];
    const float* Wo   = (const float*)d_in[8];
    const float* bo   = (const float*)d_in[9];
    float* out = (float*)d_out;

    char* ws = (char*)d_ws;
    u16* WTs = (u16*)(ws);                          // 384KB K-blocked swizzled
    u16* WOT = (u16*)(ws + 393216);                 // 128KB
    u16* Qb  = (u16*)(ws + 524288);                 // 33.55MB (also attn out)
    u16* Kb  = (u16*)(ws + 524288 + 33554432);      // 33.55MB
    u16* VTb = (u16*)(ws + 524288 + 2 * 33554432);  // 33.55MB, [b][h][n]

    prep_w<<<1024, 256, 0, stream>>>(Wq, Wk, Wv, Wo, WTs, WOT);
    qkv_gemm<<<512, 256, 0, stream>>>(x, WTs, bq, bk, bv, Qb, Kb, VTb);
    attn_kernel<<<512, 512, 0, stream>>>(Qb, Kb, VTb, mask, Qb);
    out_gemm<<<512, 256, 0, stream>>>(Qb, WOT, bo, out);
}

// Round 15
// 188.692 us; speedup vs baseline: 1.1252x; 1.1021x over previous
//
#include <hip/hip_runtime.h>
#include <stdint.h>

typedef __attribute__((ext_vector_type(8))) __bf16 bf16x8;
typedef __attribute__((ext_vector_type(4))) float f32x4;
typedef __attribute__((ext_vector_type(8))) unsigned short ushort8;
typedef __attribute__((ext_vector_type(4))) unsigned short ushort4v;
typedef unsigned short u16;
typedef unsigned int u32;

__device__ __forceinline__ u16 f2bf(float f) {
    __bf16 h = (__bf16)f;
    return __builtin_bit_cast(u16, h);
}

__device__ __forceinline__ f32x4 mfma16(bf16x8 a, bf16x8 b, f32x4 c) {
    return __builtin_amdgcn_mfma_f32_16x16x32_bf16(a, b, c, 0, 0, 0);
}

typedef __attribute__((address_space(1))) const char g_char;
typedef __attribute__((address_space(3))) char l_char;
__device__ __forceinline__ void gload_lds16(const void* g, void* l) {
    __builtin_amdgcn_global_load_lds((g_char*)g, (l_char*)l, 16, 0, 0);
}

// ---------------------------------------------------------------------------
// Weight prep:
//  WTs: kk2-blocked (BK=32), XOR-pre-swizzled bf16 W^T.
//    WTs_u16[kk2*24576 + j*32 + (c ^ ((j&3)<<3))] = W_sel[kk2*32+c][j%256]
//    (j<256: Wq, <512: Wk, <768: Wv; kk2 in 0..7, c in 0..31; rows 64B)
//  WOT[o][h] = Wo[h][o] as bf16 (out_gemm, unchanged).
// ---------------------------------------------------------------------------
__global__ __launch_bounds__(256) void prep_w(
    const float* __restrict__ Wq, const float* __restrict__ Wk,
    const float* __restrict__ Wv, const float* __restrict__ Wo,
    u16* __restrict__ WTs, u16* __restrict__ WOT)
{
    int idx = blockIdx.x * 256 + threadIdx.x;  // 0..262143
    if (idx < 196608) {
        int j = idx >> 8, k = idx & 255;
        const float* W = (j < 256) ? Wq : (j < 512) ? Wk : Wv;
        u16 v = f2bf(W[k * 256 + (j & 255)]);
        int kk2 = k >> 5, c = k & 31;
        WTs[kk2 * 24576 + j * 32 + (c ^ ((j & 3) << 3))] = v;
    } else {
        int t = idx - 196608;
        int j = t >> 8, k = t & 255;
        WOT[t] = f2bf(Wo[k * 256 + j]);
    }
}

// ---------------------------------------------------------------------------
// QKV projection r15 (= r14 + DMA dest fix): one block = 128 rows x ALL 768
// cols (A read once, 64KB swizzled LDS); B half-tiles (8KB, BK=32, pre-
// swizzled) double-buffered via global_load_lds. LDS = 80KB -> 2 blocks/CU.
// 48 steps x 1 barrier. Per i: 256 thr x 16B = 4096B, 1024B PER WAVE.
// ---------------------------------------------------------------------------
__global__ __launch_bounds__(256) void qkv_gemm(
    const float* __restrict__ X, const u16* __restrict__ WTs,
    const float* __restrict__ bQ, const float* __restrict__ bK,
    const float* __restrict__ bV,
    u16* __restrict__ outQ, u16* __restrict__ outK, u16* __restrict__ outVT)
{
    __shared__ __align__(16) u16 As[128 * 256];  // 64KB, rows 512B, XOR-swizzled
    __shared__ __align__(16) u16 Bs[2][4096];    // 2 x 8KB, rows 64B, pre-swizzled
    const int tid = threadIdx.x;
    const int m0 = blockIdx.x * 128;

    // ---- stage A once: f32 -> bf16 -> swizzled LDS ----
    #pragma unroll
    for (int i = 0; i < 32; ++i) {
        int flat = (i * 256 + tid) * 4;
        int r = flat >> 8, c = flat & 255;
        const f32x4 f = *reinterpret_cast<const f32x4*>(X + (size_t)(m0 + r) * 256 + c);
        ushort4v h;
        h.x = f2bf(f.x); h.y = f2bf(f.y); h.z = f2bf(f.z); h.w = f2bf(f.w);
        int byte = (r * 512 + c * 2) ^ ((r & 7) << 4);
        *reinterpret_cast<ushort4v*>(reinterpret_cast<char*>(As) + byte) = h;
    }

    const int lane = tid & 63, wid = tid >> 6;
    const int wr = wid >> 1, wc = wid & 1;
    const int lr = lane & 15, lg = lane >> 4;

    // tile t = cb*8 + kk2; B half-tile = contiguous 8KB at kk2 block + jbase
    auto stageB = [&](int buf, int t) {
        const int cb = t >> 3, kk2 = t & 7;
        const char* src = reinterpret_cast<const char*>(
            WTs + (size_t)kk2 * 24576 + (size_t)cb * 128 * 32);
        #pragma unroll
        for (int i = 0; i < 2; ++i) {
            int p = (i * 256 + tid) * 16;
            gload_lds16(src + p,
                reinterpret_cast<char*>(Bs[buf]) + i * 4096 + wid * 1024);
        }
    };

    stageB(0, 0);
    __syncthreads();  // A writes visible + first B half-tile landed

    for (int cb = 0; cb < 6; ++cb) {
        const int jbase = cb * 128;
        f32x4 acc[4][4];
        #pragma unroll
        for (int a = 0; a < 4; ++a)
            #pragma unroll
            for (int b = 0; b < 4; ++b) acc[a][b] = (f32x4){0.f, 0.f, 0.f, 0.f};

        for (int kk2 = 0; kk2 < 8; ++kk2) {
            const int t = cb * 8 + kk2;
            const int cur = t & 1;
            if (t < 47) stageB(cur ^ 1, t + 1);  // async DMA into other buffer

            bf16x8 af[4], bfr[4];
            #pragma unroll
            for (int mt = 0; mt < 4; ++mt) {
                int r = wr * 64 + mt * 16 + lr;
                int byte = (r * 512 + (kk2 * 32 + lg * 8) * 2) ^ ((r & 7) << 4);
                af[mt] = *reinterpret_cast<const bf16x8*>(
                    reinterpret_cast<const char*>(As) + byte);
            }
            #pragma unroll
            for (int nt = 0; nt < 4; ++nt) {
                int r = wc * 64 + nt * 16 + lr;
                int byte = (r * 64 + lg * 16) ^ ((r & 3) << 4);
                bfr[nt] = *reinterpret_cast<const bf16x8*>(
                    reinterpret_cast<const char*>(Bs[cur]) + byte);
            }
            __builtin_amdgcn_s_setprio(1);
            #pragma unroll
            for (int mt = 0; mt < 4; ++mt)
                #pragma unroll
                for (int nt = 0; nt < 4; ++nt)
                    acc[mt][nt] = mfma16(af[mt], bfr[nt], acc[mt][nt]);
            __builtin_amdgcn_s_setprio(0);

            __syncthreads();  // next B landed; Bs[cur] readers done
        }

        // epilogue for this cb: bias + relu + bf16 stores
        const float* bias = (cb < 2) ? bQ : (cb < 4) ? bK : bV;
        float bcol[4];
        #pragma unroll
        for (int nt = 0; nt < 4; ++nt)
            bcol[nt] = bias[(jbase + wc * 64 + nt * 16 + lr) & 255];
        #pragma unroll
        for (int mt = 0; mt < 4; ++mt) {
            #pragma unroll
            for (int nt = 0; nt < 4; ++nt) {
                #pragma unroll
                for (int j = 0; j < 4; ++j) {
                    float v = fmaxf(acc[mt][nt][j] + bcol[nt], 0.f);
                    u16 h = f2bf(v);
                    int row = m0 + wr * 64 + mt * 16 + lg * 4 + j;
                    int col = jbase + wc * 64 + nt * 16 + lr;
                    if (cb < 2) {
                        outQ[(size_t)row * 256 + col] = h;
                    } else if (cb < 4) {
                        outK[(size_t)row * 256 + (col - 256)] = h;
                    } else {
                        int bb = row >> 9, n = row & 511;
                        outVT[(size_t)bb * 131072 + (size_t)(col - 512) * 512 + n] = h;
                    }
                }
            }
        }
    }
}

// ---------------------------------------------------------------------------
// Flash attention r11 (unchanged): swapped QK^T, scalar softmax, b64 P path.
// ---------------------------------------------------------------------------
__global__ __launch_bounds__(512) void attn_kernel(
    const u16* __restrict__ Q, const u16* __restrict__ K,
    const u16* __restrict__ VT, const float* __restrict__ Mask,
    u16* __restrict__ Out)
{
    __shared__ __align__(16) u16 k_lds[2][32 * 256];  // 2 x 16KB, XOR-swizzled
    __shared__ __align__(16) u16 v_lds[2][256 * 32];  // 2 x 16KB, chunk-swizzled
    __shared__ __align__(16) char p_lds[8 * 1280];    // per-wave [16 q][80B]
    const int tid = threadIdx.x;          // 0..511
    const int b  = blockIdx.x & 127;      // batch; 4 blocks/batch on one XCD
    const int rb = blockIdx.x >> 7;       // 0..3
    const int lane = tid & 63, wid = tid >> 6;
    const int lr = lane & 15, lg = lane >> 4;
    const int n0 = rb * 128 + wid * 16;
    const u16* qbat = Q  + (size_t)b * 131072;
    const u16* kbat = K  + (size_t)b * 131072;
    const u16* vbat = VT + (size_t)b * 131072;
    const float* mbase = Mask + ((size_t)b * 512 + n0 + lr) * 512;
    char* pw = p_lds + wid * 1280;

    auto stage = [&](int buf, int kt) {
        #pragma unroll
        for (int i = 0; i < 2; ++i) {
            int p = (i * 512 + tid) * 16;
            int krow = p >> 9, kcol2 = p & 511;
            int scol2 = kcol2 ^ ((krow & 7) << 4);
            const char* gk = reinterpret_cast<const char*>(kbat + (size_t)(kt * 32 + krow) * 256) + scol2;
            char* lk = reinterpret_cast<char*>(k_lds[buf]) + i * 8192 + wid * 1024;
            gload_lds16(gk, lk);
            int vrow = p >> 6;
            int chunk = (p >> 4) & 3;
            int schunk = chunk ^ (vrow & 3);
            const char* gv = reinterpret_cast<const char*>(vbat + (size_t)vrow * 512 + kt * 32) + schunk * 16;
            char* lv = reinterpret_cast<char*>(v_lds[buf]) + i * 8192 + wid * 1024;
            gload_lds16(gv, lv);
        }
    };

    bf16x8 qf[8];
    #pragma unroll
    for (int ks = 0; ks < 8; ++ks)
        qf[ks] = *reinterpret_cast<const bf16x8*>(
            qbat + (size_t)(n0 + lr) * 256 + ks * 32 + lg * 8);

    stage(0, 0);
    f32x4 mf[2];
    #pragma unroll
    for (int ct = 0; ct < 2; ++ct)
        mf[ct] = __builtin_nontemporal_load(
            reinterpret_cast<const f32x4*>(mbase + ct * 16 + lg * 4));

    f32x4 acc[16];
    #pragma unroll
    for (int i = 0; i < 16; ++i) acc[i] = (f32x4){0.f, 0.f, 0.f, 0.f};
    float mreg = -__builtin_inff(), lreg = 0.f;

    __syncthreads();

    for (int kt = 0; kt < 16; ++kt) {
        const int cur = kt & 1;
        if (kt < 15) stage(cur ^ 1, kt + 1);

        u32 mb = 0;
        #pragma unroll
        for (int ct = 0; ct < 2; ++ct)
            #pragma unroll
            for (int j = 0; j < 4; ++j)
                mb |= (mf[ct][j] > 0.5f ? 1u : 0u) << (ct * 4 + j);
        if (kt < 15) {
            #pragma unroll
            for (int ct = 0; ct < 2; ++ct)
                mf[ct] = __builtin_nontemporal_load(reinterpret_cast<const f32x4*>(
                    mbase + (kt + 1) * 32 + ct * 16 + lg * 4));
        }

        f32x4 s[2];
        s[0] = (f32x4){0.f, 0.f, 0.f, 0.f};
        s[1] = (f32x4){0.f, 0.f, 0.f, 0.f};
        const char* kbase = reinterpret_cast<const char*>(k_lds[cur]);
        __builtin_amdgcn_s_setprio(1);
        #pragma unroll
        for (int ks = 0; ks < 8; ++ks) {
            #pragma unroll
            for (int ct = 0; ct < 2; ++ct) {
                int krow = ct * 16 + lr;
                int byte = (krow * 512 + (ks * 32 + lg * 8) * 2) ^ ((krow & 7) << 4);
                bf16x8 kf = *reinterpret_cast<const bf16x8*>(kbase + byte);
                s[ct] = mfma16(kf, qf[ks], s[ct]);   // SWAPPED: D = S^T
            }
        }
        __builtin_amdgcn_s_setprio(0);

        float p[2][4];
        #pragma unroll
        for (int ct = 0; ct < 2; ++ct)
            #pragma unroll
            for (int j = 0; j < 4; ++j)
                p[ct][j] = ((mb >> (ct * 4 + j)) & 1u) ? s[ct][j] : -9.0e15f;

        float r0 = p[0][0];
        r0 = fmaxf(r0, p[0][1]); r0 = fmaxf(r0, p[0][2]); r0 = fmaxf(r0, p[0][3]);
        r0 = fmaxf(r0, p[1][0]); r0 = fmaxf(r0, p[1][1]);
        r0 = fmaxf(r0, p[1][2]); r0 = fmaxf(r0, p[1][3]);
        r0 = fmaxf(r0, __shfl_xor(r0, 16));
        r0 = fmaxf(r0, __shfl_xor(r0, 32));
        bool need = (r0 > mreg);
        if (__any(need)) {
            float mnew = fmaxf(mreg, r0);
            float sc = __expf(mreg - mnew);
            mreg = mnew;
            lreg *= sc;
            #pragma unroll
            for (int ht = 0; ht < 16; ++ht) {
                acc[ht][0] *= sc; acc[ht][1] *= sc;
                acc[ht][2] *= sc; acc[ht][3] *= sc;
            }
        }
        float ps = 0.f;
        #pragma unroll
        for (int ct = 0; ct < 2; ++ct)
            #pragma unroll
            for (int j = 0; j < 4; ++j) {
                float e = __expf(p[ct][j] - mreg);
                p[ct][j] = e;
                ps += e;
            }
        lreg += ps;

        #pragma unroll
        for (int ct = 0; ct < 2; ++ct) {
            ushort4v w;
            w.x = f2bf(p[ct][0]); w.y = f2bf(p[ct][1]);
            w.z = f2bf(p[ct][2]); w.w = f2bf(p[ct][3]);
            *reinterpret_cast<ushort4v*>(pw + lr * 80 + ct * 32 + lg * 8) = w;
        }

        bf16x8 pf = *reinterpret_cast<const bf16x8*>(pw + lr * 80 + lg * 16);
        const char* vbase = reinterpret_cast<const char*>(v_lds[cur]);
        __builtin_amdgcn_s_setprio(1);
        #pragma unroll
        for (int ht = 0; ht < 16; ++ht) {
            int hrow = ht * 16 + lr;
            int byte = (hrow * 64 + lg * 16) ^ ((hrow & 3) << 4);
            bf16x8 vf = *reinterpret_cast<const bf16x8*>(vbase + byte);
            acc[ht] = mfma16(vf, pf, acc[ht]);
        }
        __builtin_amdgcn_s_setprio(0);

        __syncthreads();
    }

    float lt = lreg;
    lt += __shfl_xor(lt, 16);
    lt += __shfl_xor(lt, 32);
    float inv = 1.0f / lt;
    u16* orow = Out + ((size_t)b * 512 + n0 + lr) * 256;
    #pragma unroll
    for (int ht = 0; ht < 16; ++ht) {
        ushort4v w;
        w.x = f2bf(acc[ht][0] * inv); w.y = f2bf(acc[ht][1] * inv);
        w.z = f2bf(acc[ht][2] * inv); w.w = f2bf(acc[ht][3] * inv);
        *reinterpret_cast<ushort4v*>(orow + ht * 16 + lg * 4) = w;
    }
}

// ---------------------------------------------------------------------------
// Output projection: Out[65536,256] = relu(A[65536,256](bf16) @ Wo + bo), f32.
// ---------------------------------------------------------------------------
__global__ __launch_bounds__(256, 2) void out_gemm(
    const u16* __restrict__ A, const u16* __restrict__ WOT,
    const float* __restrict__ bO, float* __restrict__ Out)
{
    __shared__ __align__(16) u16 As[128 * 256];
    __shared__ __align__(16) u16 Bs[128 * 64];
    const int tid = threadIdx.x;
    const int m0 = blockIdx.x * 128;

    #pragma unroll
    for (int i = 0; i < 16; ++i) {
        int e = (i * 256 + tid) * 8;
        int r = e >> 8, c = e & 255;
        ushort8 d = *reinterpret_cast<const ushort8*>(A + (size_t)(m0 + r) * 256 + c);
        int byte = (r * 512 + c * 2) ^ ((r & 7) << 4);
        *reinterpret_cast<ushort8*>(reinterpret_cast<char*>(As) + byte) = d;
    }

    const int lane = tid & 63, wid = tid >> 6;
    const int wr = wid >> 1, wc = wid & 1;
    const int lr = lane & 15, lg = lane >> 4;

    for (int cb = 0; cb < 2; ++cb) {
        const int jbase = cb * 128;
        f32x4 acc[4][4];
        #pragma unroll
        for (int a = 0; a < 4; ++a)
            #pragma unroll
            for (int b = 0; b < 4; ++b) acc[a][b] = (f32x4){0.f, 0.f, 0.f, 0.f};

        for (int kk = 0; kk < 256; kk += 64) {
            __syncthreads();
            #pragma unroll
            for (int i = 0; i < 4; ++i) {
                int e = (i * 256 + tid) * 8;
                int r = e >> 6, c = e & 63;
                ushort8 d = *reinterpret_cast<const ushort8*>(WOT + (size_t)(jbase + r) * 256 + kk + c);
                int byte = (r * 128 + c * 2) ^ ((r & 7) << 4);
                *reinterpret_cast<ushort8*>(reinterpret_cast<char*>(Bs) + byte) = d;
            }
            __syncthreads();
            #pragma unroll
            for (int ks = 0; ks < 2; ++ks) {
                bf16x8 af[4], bfr[4];
                #pragma unroll
                for (int mt = 0; mt < 4; ++mt) {
                    int r = wr * 64 + mt * 16 + lr;
                    int byte = (r * 512 + (kk + ks * 32 + lg * 8) * 2) ^ ((r & 7) << 4);
                    af[mt] = *reinterpret_cast<const bf16x8*>(reinterpret_cast<const char*>(As) + byte);
                }
                #pragma unroll
                for (int nt = 0; nt < 4; ++nt) {
                    int r = wc * 64 + nt * 16 + lr;
                    int byte = (r * 128 + (ks * 32 + lg * 8) * 2) ^ ((r & 7) << 4);
                    bfr[nt] = *reinterpret_cast<const bf16x8*>(reinterpret_cast<const char*>(Bs) + byte);
                }
                #pragma unroll
                for (int mt = 0; mt < 4; ++mt)
                    #pragma unroll
                    for (int nt = 0; nt < 4; ++nt)
                        acc[mt][nt] = mfma16(af[mt], bfr[nt], acc[mt][nt]);
            }
        }
        float bcol[4];
        #pragma unroll
        for (int nt = 0; nt < 4; ++nt)
            bcol[nt] = bO[jbase + wc * 64 + nt * 16 + lr];
        #pragma unroll
        for (int mt = 0; mt < 4; ++mt) {
            #pragma unroll
            for (int nt = 0; nt < 4; ++nt) {
                #pragma unroll
                for (int j = 0; j < 4; ++j) {
                    float v = fmaxf(acc[mt][nt][j] + bcol[nt], 0.f);
                    int row = m0 + wr * 64 + mt * 16 + lg * 4 + j;
                    int col = jbase + wc * 64 + nt * 16 + lr;
                    Out[(size_t)row * 256 + col] = v;
                }
            }
        }
    }
}

// ---------------------------------------------------------------------------
extern "C" void kernel_launch(void* const* d_in, const int* in_sizes, int n_in,
                              void* d_out, int out_size, void* d_ws, size_t ws_size,
                              hipStream_t stream) {
    const float* x    = (const float*)d_in[0];
    const float* mask = (const float*)d_in[1];
    const float* Wv   = (const float*)d_in[2];
    const float* bv   = (const float*)d_in[3];
    const float* Wk   = (const float*)d_in[4];
    const float* bk   = (const float*)d_in[5];
    const float* Wq   = (const float*)d_in[6];
    const float* bq   = (const float*)d_in[7];
    const float* Wo   = (const float*)d_in[8];
    const float* bo   = (const float*)d_in[9];
    float* out = (float*)d_out;

    char* ws = (char*)d_ws;
    u16* WTs = (u16*)(ws);                          // 384KB kk2-blocked swizzled
    u16* WOT = (u16*)(ws + 393216);                 // 128KB
    u16* Qb  = (u16*)(ws + 524288);                 // 33.55MB (also attn out)
    u16* Kb  = (u16*)(ws + 524288 + 33554432);      // 33.55MB
    u16* VTb = (u16*)(ws + 524288 + 2 * 33554432);  // 33.55MB, [b][h][n]

    prep_w<<<1024, 256, 0, stream>>>(Wq, Wk, Wv, Wo, WTs, WOT);
    qkv_gemm<<<512, 256, 0, stream>>>(x, WTs, bq, bk, bv, Qb, Kb, VTb);
    attn_kernel<<<512, 512, 0, stream>>>(Qb, Kb, VTb, mask, Qb);
    out_gemm<<<512, 256, 0, stream>>>(Qb, WOT, bo, out);
}

// Round 16
// 186.950 us; speedup vs baseline: 1.1357x; 1.0093x over previous
//
#include <hip/hip_runtime.h>
#include <stdint.h>

typedef __attribute__((ext_vector_type(8))) __bf16 bf16x8;
typedef __attribute__((ext_vector_type(4))) float f32x4;
typedef __attribute__((ext_vector_type(8))) unsigned short ushort8;
typedef __attribute__((ext_vector_type(4))) unsigned short ushort4v;
typedef unsigned short u16;
typedef unsigned int u32;

__device__ __forceinline__ u16 f2bf(float f) {
    __bf16 h = (__bf16)f;
    return __builtin_bit_cast(u16, h);
}

__device__ __forceinline__ f32x4 mfma16(bf16x8 a, bf16x8 b, f32x4 c) {
    return __builtin_amdgcn_mfma_f32_16x16x32_bf16(a, b, c, 0, 0, 0);
}

typedef __attribute__((address_space(1))) const char g_char;
typedef __attribute__((address_space(3))) char l_char;
__device__ __forceinline__ void gload_lds16(const void* g, void* l) {
    __builtin_amdgcn_global_load_lds((g_char*)g, (l_char*)l, 16, 0, 0);
}

// ---------------------------------------------------------------------------
// Weight prep:
//  WTs: kk2-blocked (BK=32), chunk-swizzled bf16 W^T; 64B rows.
//    chunk ^= (j>>1)&3  (NOT j&3: rows {0,4,8,12} would 4-way-collide)
//    WTs_u16[kk2*24576 + j*32 + (c ^ (((j>>1)&3)<<3))] = W_sel[kk2*32+c][j%256]
//  WOT[o][h] = Wo[h][o] as bf16 (out_gemm, unchanged).
// ---------------------------------------------------------------------------
__global__ __launch_bounds__(256) void prep_w(
    const float* __restrict__ Wq, const float* __restrict__ Wk,
    const float* __restrict__ Wv, const float* __restrict__ Wo,
    u16* __restrict__ WTs, u16* __restrict__ WOT)
{
    int idx = blockIdx.x * 256 + threadIdx.x;  // 0..262143
    if (idx < 196608) {
        int j = idx >> 8, k = idx & 255;
        const float* W = (j < 256) ? Wq : (j < 512) ? Wk : Wv;
        u16 v = f2bf(W[k * 256 + (j & 255)]);
        int kk2 = k >> 5, c = k & 31;
        WTs[kk2 * 24576 + j * 32 + (c ^ (((j >> 1) & 3) << 3))] = v;
    } else {
        int t = idx - 196608;
        int j = t >> 8, k = t & 255;
        WOT[t] = f2bf(Wo[k * 256 + j]);
    }
}

// ---------------------------------------------------------------------------
// QKV projection r16 (= r15 + conflict-free B swizzle): one block = 128 rows
// x ALL 768 cols (A read once, 64KB swizzled LDS); B half-tiles (8KB, BK=32,
// pre-swizzled) double-buffered via global_load_lds. LDS = 80KB -> 2/CU.
// ---------------------------------------------------------------------------
__global__ __launch_bounds__(256) void qkv_gemm(
    const float* __restrict__ X, const u16* __restrict__ WTs,
    const float* __restrict__ bQ, const float* __restrict__ bK,
    const float* __restrict__ bV,
    u16* __restrict__ outQ, u16* __restrict__ outK, u16* __restrict__ outVT)
{
    __shared__ __align__(16) u16 As[128 * 256];  // 64KB, rows 512B, XOR-swizzled
    __shared__ __align__(16) u16 Bs[2][4096];    // 2 x 8KB, rows 64B, pre-swizzled
    const int tid = threadIdx.x;
    const int m0 = blockIdx.x * 128;

    // ---- stage A once: f32 -> bf16 -> swizzled LDS ----
    #pragma unroll
    for (int i = 0; i < 32; ++i) {
        int flat = (i * 256 + tid) * 4;
        int r = flat >> 8, c = flat & 255;
        const f32x4 f = *reinterpret_cast<const f32x4*>(X + (size_t)(m0 + r) * 256 + c);
        ushort4v h;
        h.x = f2bf(f.x); h.y = f2bf(f.y); h.z = f2bf(f.z); h.w = f2bf(f.w);
        int byte = (r * 512 + c * 2) ^ ((r & 7) << 4);
        *reinterpret_cast<ushort4v*>(reinterpret_cast<char*>(As) + byte) = h;
    }

    const int lane = tid & 63, wid = tid >> 6;
    const int wr = wid >> 1, wc = wid & 1;
    const int lr = lane & 15, lg = lane >> 4;

    // tile t = cb*8 + kk2; B half-tile = contiguous 8KB at kk2 block + jbase
    auto stageB = [&](int buf, int t) {
        const int cb = t >> 3, kk2 = t & 7;
        const char* src = reinterpret_cast<const char*>(
            WTs + (size_t)kk2 * 24576 + (size_t)cb * 128 * 32);
        #pragma unroll
        for (int i = 0; i < 2; ++i) {
            int p = (i * 256 + tid) * 16;
            gload_lds16(src + p,
                reinterpret_cast<char*>(Bs[buf]) + i * 4096 + wid * 1024);
        }
    };

    stageB(0, 0);
    __syncthreads();  // A writes visible + first B half-tile landed

    for (int cb = 0; cb < 6; ++cb) {
        const int jbase = cb * 128;
        f32x4 acc[4][4];
        #pragma unroll
        for (int a = 0; a < 4; ++a)
            #pragma unroll
            for (int b = 0; b < 4; ++b) acc[a][b] = (f32x4){0.f, 0.f, 0.f, 0.f};

        for (int kk2 = 0; kk2 < 8; ++kk2) {
            const int t = cb * 8 + kk2;
            const int cur = t & 1;
            if (t < 47) stageB(cur ^ 1, t + 1);  // async DMA into other buffer

            bf16x8 af[4], bfr[4];
            #pragma unroll
            for (int mt = 0; mt < 4; ++mt) {
                int r = wr * 64 + mt * 16 + lr;
                int byte = (r * 512 + (kk2 * 32 + lg * 8) * 2) ^ ((r & 7) << 4);
                af[mt] = *reinterpret_cast<const bf16x8*>(
                    reinterpret_cast<const char*>(As) + byte);
            }
            #pragma unroll
            for (int nt = 0; nt < 4; ++nt) {
                int r = wc * 64 + nt * 16 + lr;
                int byte = (r * 64 + lg * 16) ^ (((r >> 1) & 3) << 4);
                bfr[nt] = *reinterpret_cast<const bf16x8*>(
                    reinterpret_cast<const char*>(Bs[cur]) + byte);
            }
            __builtin_amdgcn_s_setprio(1);
            #pragma unroll
            for (int mt = 0; mt < 4; ++mt)
                #pragma unroll
                for (int nt = 0; nt < 4; ++nt)
                    acc[mt][nt] = mfma16(af[mt], bfr[nt], acc[mt][nt]);
            __builtin_amdgcn_s_setprio(0);

            __syncthreads();  // next B landed; Bs[cur] readers done
        }

        // epilogue for this cb: bias + relu + bf16 stores
        const float* bias = (cb < 2) ? bQ : (cb < 4) ? bK : bV;
        float bcol[4];
        #pragma unroll
        for (int nt = 0; nt < 4; ++nt)
            bcol[nt] = bias[(jbase + wc * 64 + nt * 16 + lr) & 255];
        #pragma unroll
        for (int mt = 0; mt < 4; ++mt) {
            #pragma unroll
            for (int nt = 0; nt < 4; ++nt) {
                #pragma unroll
                for (int j = 0; j < 4; ++j) {
                    float v = fmaxf(acc[mt][nt][j] + bcol[nt], 0.f);
                    u16 h = f2bf(v);
                    int row = m0 + wr * 64 + mt * 16 + lg * 4 + j;
                    int col = jbase + wc * 64 + nt * 16 + lr;
                    if (cb < 2) {
                        outQ[(size_t)row * 256 + col] = h;
                    } else if (cb < 4) {
                        outK[(size_t)row * 256 + (col - 256)] = h;
                    } else {
                        int bb = row >> 9, n = row & 511;
                        outVT[(size_t)bb * 131072 + (size_t)(col - 512) * 512 + n] = h;
                    }
                }
            }
        }
    }
}

// ---------------------------------------------------------------------------
// Flash attention r16 = r11 + conflict-free V swizzle ((row>>1)&3 both sides).
// ---------------------------------------------------------------------------
__global__ __launch_bounds__(512) void attn_kernel(
    const u16* __restrict__ Q, const u16* __restrict__ K,
    const u16* __restrict__ VT, const float* __restrict__ Mask,
    u16* __restrict__ Out)
{
    __shared__ __align__(16) u16 k_lds[2][32 * 256];  // 2 x 16KB, XOR-swizzled
    __shared__ __align__(16) u16 v_lds[2][256 * 32];  // 2 x 16KB, chunk-swizzled
    __shared__ __align__(16) char p_lds[8 * 1280];    // per-wave [16 q][80B]
    const int tid = threadIdx.x;          // 0..511
    const int b  = blockIdx.x & 127;      // batch; 4 blocks/batch on one XCD
    const int rb = blockIdx.x >> 7;       // 0..3
    const int lane = tid & 63, wid = tid >> 6;
    const int lr = lane & 15, lg = lane >> 4;
    const int n0 = rb * 128 + wid * 16;
    const u16* qbat = Q  + (size_t)b * 131072;
    const u16* kbat = K  + (size_t)b * 131072;
    const u16* vbat = VT + (size_t)b * 131072;
    const float* mbase = Mask + ((size_t)b * 512 + n0 + lr) * 512;
    char* pw = p_lds + wid * 1280;

    auto stage = [&](int buf, int kt) {
        #pragma unroll
        for (int i = 0; i < 2; ++i) {
            int p = (i * 512 + tid) * 16;
            int krow = p >> 9, kcol2 = p & 511;
            int scol2 = kcol2 ^ ((krow & 7) << 4);
            const char* gk = reinterpret_cast<const char*>(kbat + (size_t)(kt * 32 + krow) * 256) + scol2;
            char* lk = reinterpret_cast<char*>(k_lds[buf]) + i * 8192 + wid * 1024;
            gload_lds16(gk, lk);
            int vrow = p >> 6;
            int chunk = (p >> 4) & 3;
            int schunk = chunk ^ ((vrow >> 1) & 3);
            const char* gv = reinterpret_cast<const char*>(vbat + (size_t)vrow * 512 + kt * 32) + schunk * 16;
            char* lv = reinterpret_cast<char*>(v_lds[buf]) + i * 8192 + wid * 1024;
            gload_lds16(gv, lv);
        }
    };

    bf16x8 qf[8];
    #pragma unroll
    for (int ks = 0; ks < 8; ++ks)
        qf[ks] = *reinterpret_cast<const bf16x8*>(
            qbat + (size_t)(n0 + lr) * 256 + ks * 32 + lg * 8);

    stage(0, 0);
    f32x4 mf[2];
    #pragma unroll
    for (int ct = 0; ct < 2; ++ct)
        mf[ct] = __builtin_nontemporal_load(
            reinterpret_cast<const f32x4*>(mbase + ct * 16 + lg * 4));

    f32x4 acc[16];
    #pragma unroll
    for (int i = 0; i < 16; ++i) acc[i] = (f32x4){0.f, 0.f, 0.f, 0.f};
    float mreg = -__builtin_inff(), lreg = 0.f;

    __syncthreads();

    for (int kt = 0; kt < 16; ++kt) {
        const int cur = kt & 1;
        if (kt < 15) stage(cur ^ 1, kt + 1);

        u32 mb = 0;
        #pragma unroll
        for (int ct = 0; ct < 2; ++ct)
            #pragma unroll
            for (int j = 0; j < 4; ++j)
                mb |= (mf[ct][j] > 0.5f ? 1u : 0u) << (ct * 4 + j);
        if (kt < 15) {
            #pragma unroll
            for (int ct = 0; ct < 2; ++ct)
                mf[ct] = __builtin_nontemporal_load(reinterpret_cast<const f32x4*>(
                    mbase + (kt + 1) * 32 + ct * 16 + lg * 4));
        }

        f32x4 s[2];
        s[0] = (f32x4){0.f, 0.f, 0.f, 0.f};
        s[1] = (f32x4){0.f, 0.f, 0.f, 0.f};
        const char* kbase = reinterpret_cast<const char*>(k_lds[cur]);
        __builtin_amdgcn_s_setprio(1);
        #pragma unroll
        for (int ks = 0; ks < 8; ++ks) {
            #pragma unroll
            for (int ct = 0; ct < 2; ++ct) {
                int krow = ct * 16 + lr;
                int byte = (krow * 512 + (ks * 32 + lg * 8) * 2) ^ ((krow & 7) << 4);
                bf16x8 kf = *reinterpret_cast<const bf16x8*>(kbase + byte);
                s[ct] = mfma16(kf, qf[ks], s[ct]);   // SWAPPED: D = S^T
            }
        }
        __builtin_amdgcn_s_setprio(0);

        float p[2][4];
        #pragma unroll
        for (int ct = 0; ct < 2; ++ct)
            #pragma unroll
            for (int j = 0; j < 4; ++j)
                p[ct][j] = ((mb >> (ct * 4 + j)) & 1u) ? s[ct][j] : -9.0e15f;

        float r0 = p[0][0];
        r0 = fmaxf(r0, p[0][1]); r0 = fmaxf(r0, p[0][2]); r0 = fmaxf(r0, p[0][3]);
        r0 = fmaxf(r0, p[1][0]); r0 = fmaxf(r0, p[1][1]);
        r0 = fmaxf(r0, p[1][2]); r0 = fmaxf(r0, p[1][3]);
        r0 = fmaxf(r0, __shfl_xor(r0, 16));
        r0 = fmaxf(r0, __shfl_xor(r0, 32));
        bool need = (r0 > mreg);
        if (__any(need)) {
            float mnew = fmaxf(mreg, r0);
            float sc = __expf(mreg - mnew);
            mreg = mnew;
            lreg *= sc;
            #pragma unroll
            for (int ht = 0; ht < 16; ++ht) {
                acc[ht][0] *= sc; acc[ht][1] *= sc;
                acc[ht][2] *= sc; acc[ht][3] *= sc;
            }
        }
        float ps = 0.f;
        #pragma unroll
        for (int ct = 0; ct < 2; ++ct)
            #pragma unroll
            for (int j = 0; j < 4; ++j) {
                float e = __expf(p[ct][j] - mreg);
                p[ct][j] = e;
                ps += e;
            }
        lreg += ps;

        #pragma unroll
        for (int ct = 0; ct < 2; ++ct) {
            ushort4v w;
            w.x = f2bf(p[ct][0]); w.y = f2bf(p[ct][1]);
            w.z = f2bf(p[ct][2]); w.w = f2bf(p[ct][3]);
            *reinterpret_cast<ushort4v*>(pw + lr * 80 + ct * 32 + lg * 8) = w;
        }

        bf16x8 pf = *reinterpret_cast<const bf16x8*>(pw + lr * 80 + lg * 16);
        const char* vbase = reinterpret_cast<const char*>(v_lds[cur]);
        __builtin_amdgcn_s_setprio(1);
        #pragma unroll
        for (int ht = 0; ht < 16; ++ht) {
            int hrow = ht * 16 + lr;
            int byte = (hrow * 64 + lg * 16) ^ (((hrow >> 1) & 3) << 4);
            bf16x8 vf = *reinterpret_cast<const bf16x8*>(vbase + byte);
            acc[ht] = mfma16(vf, pf, acc[ht]);
        }
        __builtin_amdgcn_s_setprio(0);

        __syncthreads();
    }

    float lt = lreg;
    lt += __shfl_xor(lt, 16);
    lt += __shfl_xor(lt, 32);
    float inv = 1.0f / lt;
    u16* orow = Out + ((size_t)b * 512 + n0 + lr) * 256;
    #pragma unroll
    for (int ht = 0; ht < 16; ++ht) {
        ushort4v w;
        w.x = f2bf(acc[ht][0] * inv); w.y = f2bf(acc[ht][1] * inv);
        w.z = f2bf(acc[ht][2] * inv); w.w = f2bf(acc[ht][3] * inv);
        *reinterpret_cast<ushort4v*>(orow + ht * 16 + lg * 4) = w;
    }
}

// ---------------------------------------------------------------------------
// Output projection: Out[65536,256] = relu(A[65536,256](bf16) @ Wo + bo), f32.
// ---------------------------------------------------------------------------
__global__ __launch_bounds__(256, 2) void out_gemm(
    const u16* __restrict__ A, const u16* __restrict__ WOT,
    const float* __restrict__ bO, float* __restrict__ Out)
{
    __shared__ __align__(16) u16 As[128 * 256];
    __shared__ __align__(16) u16 Bs[128 * 64];
    const int tid = threadIdx.x;
    const int m0 = blockIdx.x * 128;

    #pragma unroll
    for (int i = 0; i < 16; ++i) {
        int e = (i * 256 + tid) * 8;
        int r = e >> 8, c = e & 255;
        ushort8 d = *reinterpret_cast<const ushort8*>(A + (size_t)(m0 + r) * 256 + c);
        int byte = (r * 512 + c * 2) ^ ((r & 7) << 4);
        *reinterpret_cast<ushort8*>(reinterpret_cast<char*>(As) + byte) = d;
    }

    const int lane = tid & 63, wid = tid >> 6;
    const int wr = wid >> 1, wc = wid & 1;
    const int lr = lane & 15, lg = lane >> 4;

    for (int cb = 0; cb < 2; ++cb) {
        const int jbase = cb * 128;
        f32x4 acc[4][4];
        #pragma unroll
        for (int a = 0; a < 4; ++a)
            #pragma unroll
            for (int b = 0; b < 4; ++b) acc[a][b] = (f32x4){0.f, 0.f, 0.f, 0.f};

        for (int kk = 0; kk < 256; kk += 64) {
            __syncthreads();
            #pragma unroll
            for (int i = 0; i < 4; ++i) {
                int e = (i * 256 + tid) * 8;
                int r = e >> 6, c = e & 63;
                ushort8 d = *reinterpret_cast<const ushort8*>(WOT + (size_t)(jbase + r) * 256 + kk + c);
                int byte = (r * 128 + c * 2) ^ ((r & 7) << 4);
                *reinterpret_cast<ushort8*>(reinterpret_cast<char*>(Bs) + byte) = d;
            }
            __syncthreads();
            #pragma unroll
            for (int ks = 0; ks < 2; ++ks) {
                bf16x8 af[4], bfr[4];
                #pragma unroll
                for (int mt = 0; mt < 4; ++mt) {
                    int r = wr * 64 + mt * 16 + lr;
                    int byte = (r * 512 + (kk + ks * 32 + lg * 8) * 2) ^ ((r & 7) << 4);
                    af[mt] = *reinterpret_cast<const bf16x8*>(reinterpret_cast<const char*>(As) + byte);
                }
                #pragma unroll
                for (int nt = 0; nt < 4; ++nt) {
                    int r = wc * 64 + nt * 16 + lr;
                    int byte = (r * 128 + (ks * 32 + lg * 8) * 2) ^ ((r & 7) << 4);
                    bfr[nt] = *reinterpret_cast<const bf16x8*>(reinterpret_cast<const char*>(Bs) + byte);
                }
                #pragma unroll
                for (int mt = 0; mt < 4; ++mt)
                    #pragma unroll
                    for (int nt = 0; nt < 4; ++nt)
                        acc[mt][nt] = mfma16(af[mt], bfr[nt], acc[mt][nt]);
            }
        }
        float bcol[4];
        #pragma unroll
        for (int nt = 0; nt < 4; ++nt)
            bcol[nt] = bO[jbase + wc * 64 + nt * 16 + lr];
        #pragma unroll
        for (int mt = 0; mt < 4; ++mt) {
            #pragma unroll
            for (int nt = 0; nt < 4; ++nt) {
                #pragma unroll
                for (int j = 0; j < 4; ++j) {
                    float v = fmaxf(acc[mt][nt][j] + bcol[nt], 0.f);
                    int row = m0 + wr * 64 + mt * 16 + lg * 4 + j;
                    int col = jbase + wc * 64 + nt * 16 + lr;
                    Out[(size_t)row * 256 + col] = v;
                }
            }
        }
    }
}

// ---------------------------------------------------------------------------
extern "C" void kernel_launch(void* const* d_in, const int* in_sizes, int n_in,
                              void* d_out, int out_size, void* d_ws, size_t ws_size,
                              hipStream_t stream) {
    const float* x    = (const float*)d_in[0];
    const float* mask = (const float*)d_in[1];
    const float* Wv   = (const float*)d_in[2];
    const float* bv   = (const float*)d_in[3];
    const float* Wk   = (const float*)d_in[4];
    const float* bk   = (const float*)d_in[5];
    const float* Wq   = (const float*)d_in[6];
    const float* bq   = (const float*)d_in[7];
    const float* Wo   = (const float*)d_in[8];
    const float* bo   = (const float*)d_in[9];
    float* out = (float*)d_out;

    char* ws = (char*)d_ws;
    u16* WTs = (u16*)(ws);                          // 384KB kk2-blocked swizzled
    u16* WOT = (u16*)(ws + 393216);                 // 128KB
    u16* Qb  = (u16*)(ws + 524288);                 // 33.55MB (also attn out)
    u16* Kb  = (u16*)(ws + 524288 + 33554432);      // 33.55MB
    u16* VTb = (u16*)(ws + 524288 + 2 * 33554432);  // 33.55MB, [b][h][n]

    prep_w<<<1024, 256, 0, stream>>>(Wq, Wk, Wv, Wo, WTs, WOT);
    qkv_gemm<<<512, 256, 0, stream>>>(x, WTs, bq, bk, bv, Qb, Kb, VTb);
    attn_kernel<<<512, 512, 0, stream>>>(Qb, Kb, VTb, mask, Qb);
    out_gemm<<<512, 256, 0, stream>>>(Qb, WOT, bo, out);
}